// Round 1
// baseline (198.124 us; speedup 1.0000x reference)
//
#include <hip/hip_runtime.h>
#include <stdint.h>

// ---------------------------------------------------------------------------
// OEQTensorProduct: x[N,576] (64x{0e,1o,2e}) (x) y[N,9] ({0e,1o,2e}) -> out[N,576]
// 11 uvw instructions, W[u=64, v=1, w=64] each, alpha = sqrt((2l3+1)/fan).
// Strategy: per edge  z_I[u,r] = sum_p (sum_q C_I[p,q,r] y[q]) x[u,p]  (VALU, fp32)
//           out_k    += alpha_I * W_I^T z_I                            (MFMA bf16)
// GEMM: M=w(64), K=u(64), N=edges*(2l3+1). W pre-transposed+alpha-scaled to bf16.
// ---------------------------------------------------------------------------

#define NEDGES 100000
#define NE     32            // edges per block
#define NBLK   (NEDGES/NE)   // 3125

typedef short    short8 __attribute__((ext_vector_type(8)));
typedef float    f32x4  __attribute__((ext_vector_type(4)));
typedef uint32_t u32x4  __attribute__((ext_vector_type(4)));

// ---------------- compile-time Wigner-3j (real basis) tables ----------------
constexpr int L1A[11] = {0,0,0,1,1,1,1,2,2,2,2};
constexpr int L2A[11] = {0,1,2,0,1,1,2,0,1,2,2};
constexpr int L3A[11] = {0,1,2,1,0,2,1,2,1,0,2};
// instr I -> weight offset I*4096 ; k-group = L3A[I]

constexpr double cfact(int n){ double r=1.0; for(int i=2;i<=n;++i) r*=(double)i; return r; }
constexpr double csqrt(double x){ if(x<=0.0) return 0.0; double g = x>1.0?x:1.0;
                                 for(int i=0;i<80;++i) g=0.5*(g+x/g); return g; }
constexpr int imax2(int a,int b){return a>b?a:b;}
constexpr int imin2(int a,int b){return a<b?a:b;}

constexpr double su2_cg(int j1,int j2,int j3,int m1,int m2,int m3){
  if(m3 != m1+m2) return 0.0;
  int vmin = imax2(imax2(-j1+j2+m3, -j1+m1), 0);
  int vmax = imin2(imin2(j2+j3+m1, j3-j1+j2), j3+m3);
  double c = csqrt((double)(2*j3+1)*cfact(j3+j1-j2)*cfact(j3-j1+j2)*cfact(j1+j2-j3)
                   *cfact(j3+m3)*cfact(j3-m3)
                   /(cfact(j1+j2+j3+1)*cfact(j1-m1)*cfact(j1+m1)*cfact(j2-m2)*cfact(j2+m2)));
  double s=0.0;
  for(int v=vmin; v<=vmax; ++v){
    double sg = ((v+j2+m2)&1)? -1.0 : 1.0;
    s += sg*cfact(j2+j3+m1-v)*cfact(j1-m1+v)
         /(cfact(v)*cfact(j3-j1+j2-v)*cfact(j3+m3-v)*cfact(j1-j2-m3+v));
  }
  return c*s;
}

struct Cplx{ double re, im; };
struct Q55 { Cplx q[5][5]; };

constexpr Q55 change_basis(int l){
  Q55 Q{};
  const double is2 = 1.0/csqrt(2.0);
  for(int m=-l;m<0;++m){
    Q.q[l+m][l-m].re =  is2;   // q[l+m, l+|m|] = 1/sqrt2
    Q.q[l+m][l+m].im = -is2;   // q[l+m, l-|m|] = -1j/sqrt2
  }
  Q.q[l][l].re = 1.0;
  for(int m=1;m<=l;++m){
    double s = (m&1)? -1.0 : 1.0;
    Q.q[l+m][l+m].re = s*is2;  // (-1)^m/sqrt2
    Q.q[l+m][l-m].im = s*is2;  // 1j*(-1)^m/sqrt2
  }
  // multiply by (-1j)^l : l=0 -> 1, l=1 -> -i, l=2 -> -1
  for(int i=0;i<5;++i) for(int j=0;j<5;++j){
    double re=Q.q[i][j].re, im=Q.q[i][j].im;
    if(l==1){ Q.q[i][j].re = im;  Q.q[i][j].im = -re; }
    else if(l==2){ Q.q[i][j].re = -re; Q.q[i][j].im = -im; }
  }
  return Q;
}

struct Tbl {
  double C[11][5][5][5];   // [I][p][q][r], zero padded
  bool   nz[11][5][5];     // any q with C!=0 for (I,p,r)
  double alpha[11];
};

constexpr Tbl build_tbl(){
  Tbl T{};
  for(int I=0;I<11;++I){
    const int l1=L1A[I], l2=L2A[I], l3=L3A[I];
    const int D1=2*l1+1, D2=2*l2+1, D3=2*l3+1;
    double cg[5][5][5]{};
    for(int a=0;a<D1;++a)for(int b=0;b<D2;++b){
      int m3 = (a-l1)+(b-l2);
      if(m3>=-l3 && m3<=l3) cg[a][b][l3+m3] = su2_cg(l1,l2,l3,a-l1,b-l2,m3);
    }
    Q55 q1 = change_basis(l1), q2 = change_basis(l2), q3 = change_basis(l3);
    Cplx T1[5][5][5]{};
    for(int i=0;i<D1;++i)for(int b=0;b<D2;++b)for(int c=0;c<D3;++c){
      double re=0,im=0;
      for(int a=0;a<D1;++a){ re += q1.q[a][i].re*cg[a][b][c]; im += q1.q[a][i].im*cg[a][b][c]; }
      T1[i][b][c].re=re; T1[i][b][c].im=im;
    }
    Cplx T2[5][5][5]{};
    for(int i=0;i<D1;++i)for(int j=0;j<D2;++j)for(int c=0;c<D3;++c){
      double re=0,im=0;
      for(int b=0;b<D2;++b){
        double qr=q2.q[b][j].re, qi=q2.q[b][j].im;
        re += qr*T1[i][b][c].re - qi*T1[i][b][c].im;
        im += qr*T1[i][b][c].im + qi*T1[i][b][c].re;
      }
      T2[i][j][c].re=re; T2[i][j][c].im=im;
    }
    double nrm2 = 0.0;
    for(int i=0;i<D1;++i)for(int j=0;j<D2;++j)for(int k=0;k<D3;++k){
      double re=0;
      for(int c=0;c<D3;++c){
        double qr=q3.q[c][k].re, qi=-q3.q[c][k].im;   // conj
        re += qr*T2[i][j][c].re - qi*T2[i][j][c].im;
      }
      T.C[I][i][j][k] = re; nrm2 += re*re;
    }
    double nrm = csqrt(nrm2);
    if(nrm > 0.0)
      for(int i=0;i<D1;++i)for(int j=0;j<D2;++j)for(int k=0;k<D3;++k) T.C[I][i][j][k] /= nrm;
    for(int i=0;i<D1;++i)for(int k=0;k<D3;++k){
      bool any=false;
      for(int j=0;j<D2;++j) if(T.C[I][i][j][k]!=0.0) any=true;
      T.nz[I][i][k]=any;
    }
    const int fan = (l3==0)?192:256;               // sum of mu1*mu2 feeding this k
    T.alpha[I] = csqrt((double)(2*l3+1)/(double)fan);
  }
  return T;
}

constexpr Tbl TBL = build_tbl();

__device__ const float c_alpha[11] = {
  (float)TBL.alpha[0],(float)TBL.alpha[1],(float)TBL.alpha[2],(float)TBL.alpha[3],
  (float)TBL.alpha[4],(float)TBL.alpha[5],(float)TBL.alpha[6],(float)TBL.alpha[7],
  (float)TBL.alpha[8],(float)TBL.alpha[9],(float)TBL.alpha[10]
};

// ---------------- device helpers ----------------
__device__ __forceinline__ uint16_t f2bf(float f){      // fp32 -> bf16 RNE
  uint32_t u = __float_as_uint(f);
  return (uint16_t)((u + 0x7fffu + ((u>>16)&1u)) >> 16);
}
__device__ __forceinline__ uint32_t pk2(float a, float b){
  return (uint32_t)f2bf(a) | ((uint32_t)f2bf(b)<<16);
}

// ---------------- W pre-transform: Wt[I][w][u] = bf16(alpha_I * W[I][u][w]) ----
__global__ __launch_bounds__(256) void prep_w(const float* __restrict__ w,
                                              uint16_t* __restrict__ wt){
  int tid = blockIdx.x*256 + threadIdx.x;
  if(tid >= 11*4096) return;
  int I = tid >> 12;
  int rem = tid & 4095;
  int wo = rem >> 6, u = rem & 63;
  wt[tid] = f2bf(c_alpha[I] * w[(I<<12) + (u<<6) + wo]);
}

// ---------------- z-stage: compute z_I and store bf16 to LDS (MFMA B layout) --
// zT LDS layout: row = col (= n_loc*D3 + r), 64 u's of 2B; 16B slot index XOR (col&7)
template<int I>
__device__ __forceinline__ void zstage(const uint32_t xp[9][4], const float yv[9],
                                       char* __restrict__ zl, int nl, int ub)
{
  constexpr int l1=L1A[I], l2=L2A[I], l3=L3A[I];
  constexpr int D1=2*l1+1, D2=2*l2+1, D3=2*l3+1;
  constexpr int PB = (l1==0)?0:((l1==1)?1:4);
  constexpr int QB = (l2==0)?0:((l2==1)?1:4);
  float z[D3][8];
  #pragma unroll
  for(int r=0;r<D3;++r)
    #pragma unroll
    for(int a=0;a<8;++a) z[r][a]=0.0f;

  #pragma unroll
  for(int p=0;p<D1;++p){
    float xv[8];
    #pragma unroll
    for(int a=0;a<4;++a){
      uint32_t u = xp[PB+p][a];
      xv[2*a]   = __uint_as_float(u<<16);
      xv[2*a+1] = __uint_as_float(u & 0xffff0000u);
    }
    #pragma unroll
    for(int r=0;r<D3;++r){
      if(TBL.nz[I][p][r]){                       // constant-folded guard
        float m = 0.0f;
        #pragma unroll
        for(int q=0;q<D2;++q){
          const float cc = (float)TBL.C[I][p][q][r];   // compile-time constant
          if(cc != 0.0f) m = fmaf(cc, yv[QB+q], m);
        }
        #pragma unroll
        for(int a=0;a<8;++a) z[r][a] = fmaf(m, xv[a], z[r][a]);
      }
    }
  }
  #pragma unroll
  for(int r=0;r<D3;++r){
    u32x4 v = { pk2(z[r][0],z[r][1]), pk2(z[r][2],z[r][3]),
                pk2(z[r][4],z[r][5]), pk2(z[r][6],z[r][7]) };
    const int c = nl*D3 + r;
    *(u32x4*)(zl + c*128 + ((ub*16) ^ ((c&7)<<4))) = v;
  }
}

// ---------------- MFMA stage: acc[ct] += Wt_I^T-block * zT-block ----------------
template<int I, int NT>
__device__ __forceinline__ void mstage(f32x4* acc, const uint16_t* __restrict__ wt,
                                       const char* __restrict__ zl,
                                       int wave, int lmod, int ldiv)
{
  // A[m=w][k=u]: m = lane%16 (+16*wave), k = 8*(lane/16)+e  -> Wt rows contiguous in u
  const uint16_t* wp = wt + ((I*64 + wave*16 + lmod)*64 + ldiv*8);
  const short8 A0 = *(const short8*)(wp);        // u 0..31
  const short8 A1 = *(const short8*)(wp + 32);   // u 32..63
  #pragma unroll
  for(int ct=0; ct<NT; ++ct){
    const int c = ct*16 + lmod;                  // B col = lane%16
    const char* base = zl + c*128;
    const short8 B0 = *(const short8*)(base + ((ldiv*16)     ^ ((c&7)<<4)));
    const short8 B1 = *(const short8*)(base + (((ldiv+4)*16) ^ ((c&7)<<4)));
    acc[ct] = __builtin_amdgcn_mfma_f32_16x16x32_bf16(A0, B0, acc[ct], 0,0,0);
    acc[ct] = __builtin_amdgcn_mfma_f32_16x16x32_bf16(A1, B1, acc[ct], 0,0,0);
  }
}

// ---------------- one k-group: zero acc, loop instrs, write out ----------------
template<int NT, int D3, int KOFF, int... Is>
__device__ __forceinline__ void kgroup(const uint32_t xp[9][4], const float yv[9],
                                       char* __restrict__ zl, const uint16_t* __restrict__ wt,
                                       float* __restrict__ out, int n0,
                                       int nl, int ub, int wave, int lmod, int ldiv)
{
  f32x4 acc[NT];
  #pragma unroll
  for(int i=0;i<NT;++i) acc[i] = (f32x4){0.f,0.f,0.f,0.f};

  // for each instruction: stage z, barrier, MFMA, barrier (zl reused)
  ((zstage<Is>(xp, yv, zl, nl, ub),
    __syncthreads(),
    mstage<Is, NT>(acc, wt, zl, wave, lmod, ldiv),
    __syncthreads()), ...);

  // D layout: row(w) = 4*(lane/16)+reg, col = lane%16
  #pragma unroll
  for(int ct=0; ct<NT; ++ct){
    const int c   = ct*16 + lmod;
    const int nlc = c / D3, r = c % D3;
    float* o = out + (long)(n0 + nlc)*576 + KOFF + (wave*16 + ldiv*4)*D3 + r;
    #pragma unroll
    for(int j=0;j<4;++j) o[j*D3] = acc[ct][j];
  }
}

// ---------------- main kernel ----------------
__global__ __launch_bounds__(256) void tp_main(const float* __restrict__ x,
                                               const float* __restrict__ y,
                                               const uint16_t* __restrict__ wt,
                                               float* __restrict__ out)
{
  __shared__ char zlds[160*128] __attribute__((aligned(16)));  // 20480 B
  const int t  = threadIdx.x;
  const int nl = t>>3, ub = t&7;                 // edge-local, u-block (8 u's)
  const int n0 = blockIdx.x*NE;
  const long n = (long)n0 + nl;

  float yv[9];
  #pragma unroll
  for(int q=0;q<9;++q) yv[q] = y[n*9+q];

  // x -> packed bf16 registers xp[p_global][u_pair] (u = 2a, 2a+1 of this u-block)
  uint32_t xp[9][4];
  {
    const float* xr = x + n*576;
    const float4 a0 = *(const float4*)(xr + ub*8);
    const float4 a1 = *(const float4*)(xr + ub*8 + 4);
    xp[0][0]=pk2(a0.x,a0.y); xp[0][1]=pk2(a0.z,a0.w);
    xp[0][2]=pk2(a1.x,a1.y); xp[0][3]=pk2(a1.z,a1.w);
    float f1[24];
    {
      const float4* p1 = (const float4*)(xr + 64 + ub*24);
      #pragma unroll
      for(int i=0;i<6;++i){ float4 v=p1[i]; f1[4*i]=v.x; f1[4*i+1]=v.y; f1[4*i+2]=v.z; f1[4*i+3]=v.w; }
    }
    #pragma unroll
    for(int p=0;p<3;++p)
      #pragma unroll
      for(int a=0;a<4;++a) xp[1+p][a] = pk2(f1[(2*a)*3+p], f1[(2*a+1)*3+p]);
    float f2[40];
    {
      const float4* p2 = (const float4*)(xr + 256 + ub*40);
      #pragma unroll
      for(int i=0;i<10;++i){ float4 v=p2[i]; f2[4*i]=v.x; f2[4*i+1]=v.y; f2[4*i+2]=v.z; f2[4*i+3]=v.w; }
    }
    #pragma unroll
    for(int p=0;p<5;++p)
      #pragma unroll
      for(int a=0;a<4;++a) xp[4+p][a] = pk2(f2[(2*a)*5+p], f2[(2*a+1)*5+p]);
  }

  const int wave = t>>6, lane = t&63;
  const int lmod = lane&15, ldiv = lane>>4;

  // k=0 (l3=0, koff 0,  cols 32):  I = 0:(000) 4:(110) 9:(220)
  kgroup<2, 1, 0,   0,4,9 >(xp, yv, zlds, wt, out, n0, nl, ub, wave, lmod, ldiv);
  // k=1 (l3=1, koff 64, cols 96):  I = 1:(011) 3:(101) 6:(121) 8:(211)
  kgroup<6, 3, 64,  1,3,6,8>(xp, yv, zlds, wt, out, n0, nl, ub, wave, lmod, ldiv);
  // k=2 (l3=2, koff 256,cols 160): I = 2:(022) 5:(112) 7:(202) 10:(222)
  kgroup<10,5, 256, 2,5,7,10>(xp, yv, zlds, wt, out, n0, nl, ub, wave, lmod, ldiv);
}

// ---------------- launch ----------------
extern "C" void kernel_launch(void* const* d_in, const int* in_sizes, int n_in,
                              void* d_out, int out_size, void* d_ws, size_t ws_size,
                              hipStream_t stream)
{
  const float* x = (const float*)d_in[0];
  const float* y = (const float*)d_in[1];
  const float* w = (const float*)d_in[2];
  uint16_t* wt = (uint16_t*)d_ws;                 // 11*4096*2 = 90112 B
  prep_w<<<176, 256, 0, stream>>>(w, wt);
  tp_main<<<NBLK, 256, 0, stream>>>(x, y, wt, (float*)d_out);
}